// Round 20
// baseline (133.816 us; speedup 1.0000x reference)
//
#include <hip/hip_runtime.h>
#include <hip/hip_fp16.h>
#include <math.h>

// ---------------------------------------------------------------------------
// Spherical CNN regression forward (MAXL=3, 2 layers, TAU_IN=16, TAU_H=32).
// 5-launch pipeline with SYMMETRY-REDUCED A (verified round-16 structure)
// + XCD-aware bijective block swizzle (bit-identical output, L2 locality).
//   k_in_cg0:  [0..B/8)  front: parts->LDS, thread=(elem,c) full chain -> A
//              [B/8..+736) WT merge+realification (tiled + col-permuted)
//   k_gemm_all (layer0) -> HB   (verified structure, reduced K')
//   k_cg_all<true> (layer1 norm+CG, unique pairs) -> A
//   k_gemm_all (layer1) -> HA
//   k_final: norms + MLP -> out (verified)
// Unique K': L0=256, L1=384, L2=448, L3=384 (KT = 8,12,14,12). A = 51.9 MB.
// A layout: [mt][kt][lane=(kb*16+ar)][8 halves]; WT tiled [nt][kt][lane][8].
// ws layout: [WT 376832 B][HA B*2048 B][HB B*2048 B][A0|A1|A2|A3]
// ---------------------------------------------------------------------------

typedef _Float16 f16x8 __attribute__((ext_vector_type(8)));
typedef float f32x4 __attribute__((ext_vector_type(4)));

constexpr int kPS[5] = {0, 4, 13, 24, 34};
constexpr unsigned char kP1[34] = {
    0, 1, 2, 3,
    0, 1, 1, 1, 2, 2, 2, 3, 3,
    0, 1, 1, 1, 2, 2, 2, 2, 3, 3, 3,
    0, 1, 1, 2, 2, 2, 3, 3, 3, 3};
constexpr unsigned char kP2[34] = {
    0, 1, 2, 3,
    1, 0, 1, 2, 1, 2, 3, 2, 3,
    2, 1, 2, 3, 0, 1, 2, 3, 1, 2, 3,
    3, 2, 3, 1, 2, 3, 0, 1, 2, 3};
constexpr int kCGCoff[5] = {0, 28, 217, 602, 1092};
#define CGC_TOTAL 1092

// Unique-pair tables (first-occurrence order; dup = later (l2,l1) twin).
constexpr int kU_PS[5] = {0, 4, 10, 17, 23};
constexpr int kUsrc[23] = {0, 1, 2, 3,
                           0, 2, 3, 5, 6, 8,
                           0, 1, 2, 3, 6, 7, 10,
                           0, 1, 2, 4, 5, 9};
constexpr int kUdup[23] = {-1, -1, -1, -1,
                           1, -1, 4, -1, 7, -1,
                           4, -1, 5, 8, -1, 9, -1,
                           6, 3, 7, -1, 8, -1};
constexpr int kUsgn[23] = {1, 1, 1, 1,
                           1, 1, 1, 1, 1, 1,
                           1, 1, -1, 1, 1, -1, 1,
                           1, 1, -1, 1, 1, 1};
constexpr int kKpU[4] = {256, 384, 448, 384};        // unique K' per L
constexpr int kWToffU[4] = {0, 16384, 40960, 69632}; // half offsets within layer
#define WT_LAYER_U 94208                              // halves per layer

// XCD-aware bijective block swizzle (requires gridDim.x % 8 == 0).
__device__ __forceinline__ int swz8(int bid, int n) {
    int q = n >> 3;
    return (bid & 7) * q + (bid >> 3);
}

// ---------------- compile-time compact CG table ----------------------------
constexpr double cfact(int n) {
    double r = 1.0;
    for (int i = 2; i <= n; ++i) r *= (double)i;
    return r;
}
constexpr double csqrt(double x) {
    double g = (x > 1.0) ? x : 1.0;
    for (int it = 0; it < 64; ++it) g = 0.5 * (g + x / g);
    return g;
}
constexpr double cg_coef(int l1, int l2, int L, int m1, int m2) {
    int M = m1 + m2;
    double pre = csqrt((2.0 * L + 1.0) * cfact(l1 + l2 - L) * cfact(l1 - l2 + L) *
                       cfact(-l1 + l2 + L) / cfact(l1 + l2 + L + 1));
    pre *= csqrt(cfact(L + M) * cfact(L - M) * cfact(l1 - m1) * cfact(l1 + m1) *
                 cfact(l2 - m2) * cfact(l2 + m2));
    double s = 0.0;
    for (int k = 0; k <= l1 + l2 - L; ++k) {
        int u2 = l1 - m1 - k, u3 = l2 + m2 - k;
        int u4 = L - l2 + m1 + k, u5 = L - l1 - m2 + k;
        if (u2 < 0 || u3 < 0 || u4 < 0 || u5 < 0) continue;
        double d = cfact(k) * cfact(l1 + l2 - L - k) * cfact(u2) * cfact(u3) *
                   cfact(u4) * cfact(u5);
        s += ((k & 1) ? -1.0 : 1.0) / d;
    }
    return pre * s;
}
struct CGCTable {
    float v[CGC_TOTAL];
};
constexpr CGCTable makeCGC() {
    CGCTable T{};
    for (int t = 0; t < CGC_TOTAL; ++t) {
        int L = 0;
        while (t >= kCGCoff[L + 1]) ++L;
        int rloc = t - kCGCoff[L];
        int r = rloc / 7, i = rloc % 7;
        int nM = 2 * L + 1;
        int pl = r / nM, M = r % nM;
        int l1 = kP1[kPS[L] + pl], l2 = kP2[kPS[L] + pl];
        float val = 0.0f;
        int j = (M - L) - (i - l1) + l2;
        if (i <= 2 * l1 && j >= 0 && j <= 2 * l2)
            val = (float)cg_coef(l1, l2, L, i - l1, j - l2);
        T.v[t] = val;
    }
    return T;
}
constexpr CGCTable kCGC_CE = makeCGC();

// ---------------- compile-time CG product emission -------------------------
template <int LL>
__device__ __forceinline__ void norm_l(float2 (&hv)[16]) {
    float s = 0.f;
#pragma unroll
    for (int m = 0; m < 2 * LL + 1; ++m) {
        float2 v = hv[LL * LL + m];
        s += v.x * v.x + v.y * v.y;
    }
    float inv = 1.0f / sqrtf(s);
#pragma unroll
    for (int m = 0; m < 2 * LL + 1; ++m) {
        hv[LL * LL + m].x *= inv;
        hv[LL * LL + m].y *= inv;
    }
}

template <int L, int PS, int R, int I>
__device__ __forceinline__ void cg_term(const float2 (&hv)[16], float2& acc) {
    if constexpr (I < 7) {
        constexpr int nM = 2 * L + 1;
        constexpr int pl = R / nM, M = R % nM;
        constexpr int l1 = kP1[PS + pl], l2 = kP2[PS + pl];
        constexpr float coef = kCGC_CE.v[kCGCoff[L] + R * 7 + I];
        if constexpr (coef != 0.0f) {
            constexpr int jj = (M - L) - (I - l1) + l2;
            constexpr int s1 = l1 * l1 + I, s2 = l2 * l2 + jj;
            float2 a = hv[s1], b = hv[s2];
            acc.x += coef * (a.x * b.x - a.y * b.y);
            acc.y += coef * (a.x * b.y + a.y * b.x);
        }
        cg_term<L, PS, R, I + 1>(hv, acc);
    }
}

// Rows of unique pair U (source pair kUsrc): fragment-tiled store with new KT.
template <int L, int PS, int NU, int U, int M>
__device__ __forceinline__ void uRows(const float2 (&hv)[16], __half2* __restrict__ A2,
                                      int elemBase, int coff) {
    if constexpr (M < 2 * L + 1) {
        constexpr int PLo = kUsrc[kU_PS[L] + U];
        constexpr int KT = kKpU[L] / 32;
        float2 acc = make_float2(0.f, 0.f);
        cg_term<L, PS, PLo*(2 * L + 1) + M, 0>(hv, acc);
        int row = elemBase + M;
        A2[((row >> 4) * KT + 2 * U) * 256 + coff + ((row & 15) << 2)] =
            __float22half2_rn(acc);
        uRows<L, PS, NU, U, M + 1>(hv, A2, elemBase, coff);
    }
}

template <int L, int PS, int NU, int U>
__device__ __forceinline__ void pairEmitU(const float2 (&hv)[16],
                                          __half2* __restrict__ A2, int elemBase,
                                          int coff) {
    if constexpr (U < NU) {
        uRows<L, PS, NU, U, 0>(hv, A2, elemBase, coff);
        pairEmitU<L, PS, NU, U + 1>(hv, A2, elemBase, coff);
    }
}

template <int L, int PS, int NU, bool NORM>
__device__ __forceinline__ void cg_body(const __half2* __restrict__ Hin,
                                        __half2* __restrict__ A2, int elem, int c) {
    float2 hv[16];
#pragma unroll
    for (int s = 0; s < 16; ++s) hv[s] = __half22float2(Hin[elem * 512 + s * 32 + c]);
    if constexpr (NORM) {
        norm_l<0>(hv);
        norm_l<1>(hv);
        norm_l<2>(hv);
        norm_l<3>(hv);
    }
    const int coff = ((c >> 4) << 8) + (((c >> 2) & 3) << 6) + (c & 3);
    pairEmitU<L, PS, NU, 0>(hv, A2, elem * (2 * L + 1), coff);
}

// ---------------- per-thread input matmul (W cached in regs) ---------------
template <int LSET>
__device__ __forceinline__ void in_mm(const float2* __restrict__ stgE,
                                      const float* __restrict__ Wi, int c,
                                      float2 (&hv)[16]) {
    constexpr int s0 = LSET * LSET, ns = 2 * LSET + 1;
    float2 w[16];
#pragma unroll
    for (int k = 0; k < 16; ++k) w[k] = *(const float2*)(Wi + (k * 32 + c) * 2);
#pragma unroll
    for (int s = 0; s < ns; ++s) {
        float2 acc = make_float2(0.f, 0.f);
#pragma unroll
        for (int k = 0; k < 16; ++k) {
            float2 a = stgE[(s0 + s) * 16 + k];
            acc.x += a.x * w[k].x - a.y * w[k].y;
            acc.y += a.x * w[k].y + a.y * w[k].x;
        }
        hv[s0 + s] = acc;
    }
}

// ---------------- merged front kernel: input+norm+cg0  ||  WT --------------
__global__ void __launch_bounds__(256) k_in_cg0(
    const float* __restrict__ p0, const float* __restrict__ p1,
    const float* __restrict__ p2, const float* __restrict__ p3,
    const float* __restrict__ Wi0, const float* __restrict__ Wi1,
    const float* __restrict__ Wi2, const float* __restrict__ Wi3,
    const float* __restrict__ h00, const float* __restrict__ h01,
    const float* __restrict__ h02, const float* __restrict__ h03,
    const float* __restrict__ h10, const float* __restrict__ h11,
    const float* __restrict__ h12, const float* __restrict__ h13,
    __half* __restrict__ WT, __half2* __restrict__ A0, __half2* __restrict__ A1,
    __half2* __restrict__ A2_, __half2* __restrict__ A3, int nin) {
    const int tid = threadIdx.x;
    const int bid = swz8(blockIdx.x, gridDim.x);

    if (bid >= nin) {
        // ---- WT merge + realification (unique pairs, tiled) ----
        int t = (bid - nin) * 256 + tid;  // [0, 2*WT_LAYER_U)
        int layer = t / WT_LAYER_U, rem = t % WT_LAYER_U;
        int L;
        if (rem < 16384) L = 0;
        else if (rem < 40960) L = 1;
        else if (rem < 69632) L = 2;
        else L = 3;
        int rem2 = rem - kWToffU[L];
        int KT = kKpU[L] / 32;
        int tile = rem2 >> 9, within = rem2 & 511;
        int lane = within >> 3, e8 = within & 7;
        int nt = tile / KT, kt = tile - nt * KT;
        int nr = lane & 15, kb = lane >> 4;
        int np = 2 * nr + (nt & 1) + 32 * (nt >> 1);  // col-perm
        int kp = kt * 32 + kb * 8 + e8;
        int q = kp >> 1, s = kp & 1, cW = np >> 1, tt = np & 1;
        int u = q >> 5, qloc = q & 31;
        int ub = kU_PS[L] + u;
        int PLo = kUsrc[ub], PDo = kUdup[ub];
        float sg = (float)kUsgn[ub];
        const float* W = (layer == 0) ? (L == 0 ? h00 : L == 1 ? h01 : L == 2 ? h02 : h03)
                                      : (L == 0 ? h10 : L == 1 ? h11 : L == 2 ? h12 : h13);
        float wr = W[((PLo * 32 + qloc) * 32 + cW) * 2];
        float wi = W[((PLo * 32 + qloc) * 32 + cW) * 2 + 1];
        if (PDo >= 0) {
            wr += sg * W[((PDo * 32 + qloc) * 32 + cW) * 2];
            wi += sg * W[((PDo * 32 + qloc) * 32 + cW) * 2 + 1];
        }
        float v = (tt == 0) ? (s == 0 ? wr : -wi) : (s == 0 ? wi : wr);
        WT[t] = __float2half(v);
        return;
    }

    // ---- stage parts for 8 elements ----
    __shared__ float2 stg[8][256];
    for (int idx = tid; idx < 2048; idx += 256) {
        int e = idx >> 8, r = idx & 255;
        int slot = r >> 4, k = r & 15;
        int l = (slot >= 9) + (slot >= 4) + (slot >= 1);
        int m = slot - l * l;
        const float* src = (l == 0) ? p0 : (l == 1) ? p1 : (l == 2) ? p2 : p3;
        src += ((size_t)((bid * 8 + e) * (2 * l + 1) + m) * 16 + k) * 2;
        stg[e][r] = make_float2(src[0], src[1]);
    }
    __syncthreads();

    // ---- thread (elem, c): matmul -> norm -> CG (unique pairs) ----
    const int e = tid >> 5, c = tid & 31;
    const int elem = bid * 8 + e;
    const float2* stgE = &stg[e][0];
    float2 hv[16];
    in_mm<0>(stgE, Wi0, c, hv);
    in_mm<1>(stgE, Wi1, c, hv);
    in_mm<2>(stgE, Wi2, c, hv);
    in_mm<3>(stgE, Wi3, c, hv);
    norm_l<0>(hv);
    norm_l<1>(hv);
    norm_l<2>(hv);
    norm_l<3>(hv);

    const int coff = ((c >> 4) << 8) + (((c >> 2) & 3) << 6) + (c & 3);
    pairEmitU<0, 0, 4, 0>(hv, A0, elem * 1, coff);
    pairEmitU<1, 4, 6, 0>(hv, A1, elem * 3, coff);
    pairEmitU<2, 13, 7, 0>(hv, A2_, elem * 5, coff);
    pairEmitU<3, 24, 6, 0>(hv, A3, elem * 7, coff);
}

// ---------------- CG layer-1 kernel (unique pairs) -------------------------
template <bool NORM>
__global__ void __launch_bounds__(256) k_cg_all(const __half2* __restrict__ Hin,
                                                __half2* __restrict__ A0,
                                                __half2* __restrict__ A1,
                                                __half2* __restrict__ A2_,
                                                __half2* __restrict__ A3, int nbseg) {
    const int tid = threadIdx.x;
    const int wave = tid >> 6, lane = tid & 63;
    const int c = lane & 31, h = lane >> 5;
    int bid = swz8(blockIdx.x, gridDim.x);
    if (bid < nbseg) {
        int elem = (bid * 4 + wave) * 2 + h;
        cg_body<0, 0, 4, NORM>(Hin, A0, elem, c);
    } else if (bid < 2 * nbseg) {
        int elem = ((bid - nbseg) * 4 + wave) * 2 + h;
        cg_body<1, 4, 6, NORM>(Hin, A1, elem, c);
    } else if (bid < 3 * nbseg) {
        int elem = ((bid - 2 * nbseg) * 4 + wave) * 2 + h;
        cg_body<2, 13, 7, NORM>(Hin, A2_, elem, c);
    } else {
        int elem = ((bid - 3 * nbseg) * 4 + wave) * 2 + h;
        cg_body<3, 24, 6, NORM>(Hin, A3, elem, c);
    }
}

// ---------------- GEMM (verified structure, reduced K') --------------------
template <int L>
__device__ __forceinline__ void gemm_body(const _Float16* __restrict__ A,
                                          const _Float16* __restrict__ WT,
                                          __half2* __restrict__ Hout, int blk, int tid) {
    constexpr int nM = 2 * L + 1, KT = kKpU[L] / 32;
    const int wave = tid >> 6, lane = tid & 63;
    const int mt0 = blk * 8 + wave * 2, mt1 = mt0 + 1;
    const int ar = lane & 15, kb = lane >> 4;

    const _Float16* Ap0 = A + (size_t)(mt0 * KT) * 512 + lane * 8;
    const _Float16* Ap1 = A + (size_t)(mt1 * KT) * 512 + lane * 8;
    const _Float16* Wp = WT + lane * 8;

    f32x4 d00 = {0.f, 0.f, 0.f, 0.f}, d01 = d00, d02 = d00, d03 = d00;
    f32x4 d10 = d00, d11 = d00, d12 = d00, d13 = d00;
#pragma unroll 2
    for (int kt = 0; kt < KT; ++kt) {
        f16x8 a0 = *(const f16x8*)(Ap0 + kt * 512);
        f16x8 a1 = *(const f16x8*)(Ap1 + kt * 512);
        f16x8 w0 = *(const f16x8*)(Wp + (0 * KT + kt) * 512);
        f16x8 w1 = *(const f16x8*)(Wp + (1 * KT + kt) * 512);
        f16x8 w2 = *(const f16x8*)(Wp + (2 * KT + kt) * 512);
        f16x8 w3 = *(const f16x8*)(Wp + (3 * KT + kt) * 512);
        d00 = __builtin_amdgcn_mfma_f32_16x16x32_f16(a0, w0, d00, 0, 0, 0);
        d01 = __builtin_amdgcn_mfma_f32_16x16x32_f16(a0, w1, d01, 0, 0, 0);
        d02 = __builtin_amdgcn_mfma_f32_16x16x32_f16(a0, w2, d02, 0, 0, 0);
        d03 = __builtin_amdgcn_mfma_f32_16x16x32_f16(a0, w3, d03, 0, 0, 0);
        d10 = __builtin_amdgcn_mfma_f32_16x16x32_f16(a1, w0, d10, 0, 0, 0);
        d11 = __builtin_amdgcn_mfma_f32_16x16x32_f16(a1, w1, d11, 0, 0, 0);
        d12 = __builtin_amdgcn_mfma_f32_16x16x32_f16(a1, w2, d12, 0, 0, 0);
        d13 = __builtin_amdgcn_mfma_f32_16x16x32_f16(a1, w3, d13, 0, 0, 0);
    }

    const int rowb0 = mt0 * 16 + kb * 4, rowb1 = mt1 * 16 + kb * 4;
#pragma unroll
    for (int r = 0; r < 4; ++r) {
        int row = rowb0 + r;
        int e = row / nM, M = row - e * nM;
        int base = e * 512 + (L * L + M) * 32;
        Hout[base + ar] = __floats2half2_rn(d00[r], d01[r]);
        Hout[base + 16 + ar] = __floats2half2_rn(d02[r], d03[r]);
    }
#pragma unroll
    for (int r = 0; r < 4; ++r) {
        int row = rowb1 + r;
        int e = row / nM, M = row - e * nM;
        int base = e * 512 + (L * L + M) * 32;
        Hout[base + ar] = __floats2half2_rn(d10[r], d11[r]);
        Hout[base + 16 + ar] = __floats2half2_rn(d12[r], d13[r]);
    }
}

__global__ void __launch_bounds__(256) k_gemm_all(
    const _Float16* __restrict__ A0, const _Float16* __restrict__ A1,
    const _Float16* __restrict__ A2_, const _Float16* __restrict__ A3,
    const _Float16* __restrict__ WT, __half2* __restrict__ Hout, int nb) {
    const int tid = threadIdx.x;
    int bid = swz8(blockIdx.x, gridDim.x);
    if (bid < nb) {
        gemm_body<0>(A0, WT + kWToffU[0], Hout, bid, tid);
    } else if (bid < 4 * nb) {
        gemm_body<1>(A1, WT + kWToffU[1], Hout, bid - nb, tid);
    } else if (bid < 9 * nb) {
        gemm_body<2>(A2_, WT + kWToffU[2], Hout, bid - 4 * nb, tid);
    } else {
        gemm_body<3>(A3, WT + kWToffU[3], Hout, bid - 9 * nb, tid);
    }
}

// ---------------- final norms + MLP (verified) -----------------------------
__global__ void __launch_bounds__(128) k_final(const __half2* __restrict__ H,
                                               const float* __restrict__ W1,
                                               const float* __restrict__ b1,
                                               const float* __restrict__ W2,
                                               const float* __restrict__ b2,
                                               float* __restrict__ out) {
    __shared__ float shv[392];
    const int tid = threadIdx.x;
    const int b = swz8(blockIdx.x, gridDim.x);
    {
        int l = tid >> 5, c = tid & 31, off = l * l, n = 2 * l + 1;
        float s = 0.f;
        for (int m = 0; m < n; ++m) {
            float2 v = __half22float2(H[b * 512 + (off + m) * 32 + c]);
            s += v.x * v.x + v.y * v.y;
        }
        shv[tid] = sqrtf(s);
    }
    __syncthreads();
#pragma unroll
    for (int rr = 0; rr < 2; ++rr) {
        int j = tid + rr * 128;
        float acc = b1[j];
        for (int i = 0; i < 128; ++i) acc += shv[i] * W1[i * 256 + j];
        shv[128 + j] = tanhf(acc);
    }
    __syncthreads();
    float partial = shv[128 + tid] * W2[tid] + shv[256 + tid] * W2[tid + 128];
#pragma unroll
    for (int off = 32; off > 0; off >>= 1) partial += __shfl_down(partial, off);
    if ((tid & 63) == 0) shv[384 + (tid >> 6)] = partial;
    __syncthreads();
    if (tid == 0) out[b] = shv[384] + shv[385] + b2[0];
}

extern "C" void kernel_launch(void* const* d_in, const int* in_sizes, int n_in,
                              void* d_out, int out_size, void* d_ws, size_t ws_size,
                              hipStream_t stream) {
    (void)n_in;
    (void)ws_size;
    (void)out_size;
    const int B = in_sizes[0] / 32;  // part_0 is [B,1,16,2]

    char* ws = (char*)d_ws;
    // ws layout (bytes): WT | HA | HB | A0 | A1 | A2 | A3
    __half* WTh = (__half*)ws;
    _Float16* WTf = (_Float16*)ws;
    size_t off = 376832;  // 2*WT_LAYER_U*2 bytes
    __half2* HA = (__half2*)(ws + off);
    off += (size_t)B * 2048;
    __half2* HB = (__half2*)(ws + off);
    off += (size_t)B * 2048;
    __half* Ab = (__half*)(ws + off);
    // per-L A offsets in halves: sizes B*nM*KpU
    size_t a0 = 0;
    size_t a1 = a0 + (size_t)B * 1 * 256;
    size_t a2 = a1 + (size_t)B * 3 * 384;
    size_t a3 = a2 + (size_t)B * 5 * 448;

    __half2* A0h = (__half2*)(Ab + a0);
    __half2* A1h = (__half2*)(Ab + a1);
    __half2* A2h = (__half2*)(Ab + a2);
    __half2* A3h = (__half2*)(Ab + a3);
    _Float16* A0f = (_Float16*)(Ab + a0);
    _Float16* A1f = (_Float16*)(Ab + a1);
    _Float16* A2f = (_Float16*)(Ab + a2);
    _Float16* A3f = (_Float16*)(Ab + a3);

    const int nin = B / 8;
    const int nwt = 2 * WT_LAYER_U / 256;  // 736
    const int nbseg = B / 8, nb = B / 128;

    // ---- front: input+norm+cg0 || WT ----
    hipLaunchKernelGGL(k_in_cg0, dim3(nin + nwt), dim3(256), 0, stream,
                       (const float*)d_in[0], (const float*)d_in[1],
                       (const float*)d_in[2], (const float*)d_in[3],
                       (const float*)d_in[4], (const float*)d_in[5],
                       (const float*)d_in[6], (const float*)d_in[7],
                       (const float*)d_in[8], (const float*)d_in[9],
                       (const float*)d_in[10], (const float*)d_in[11],
                       (const float*)d_in[12], (const float*)d_in[13],
                       (const float*)d_in[14], (const float*)d_in[15], WTh, A0h, A1h,
                       A2h, A3h, nin);

    // ---- layer 0 GEMM -> HB ----
    hipLaunchKernelGGL(k_gemm_all, dim3(16 * nb), dim3(256), 0, stream,
                       A0f, A1f, A2f, A3f, WTf + 0 * WT_LAYER_U, HB, nb);

    // ---- layer 1: CG (normalize) -> A ----
    hipLaunchKernelGGL((k_cg_all<true>), dim3(4 * nbseg), dim3(256), 0, stream, HB,
                       A0h, A1h, A2h, A3h, nbseg);

    // ---- layer 1 GEMM -> HA ----
    hipLaunchKernelGGL(k_gemm_all, dim3(16 * nb), dim3(256), 0, stream,
                       A0f, A1f, A2f, A3f, WTf + 1 * WT_LAYER_U, HA, nb);

    // ---- final ----
    hipLaunchKernelGGL(k_final, dim3(B), dim3(128), 0, stream, HA,
                       (const float*)d_in[16], (const float*)d_in[17],
                       (const float*)d_in[18], (const float*)d_in[19], (float*)d_out);
}

// Round 21
// 94.526 us; speedup vs baseline: 1.4157x; 1.4157x over previous
//
#include <hip/hip_runtime.h>
#include <hip/hip_fp16.h>
#include <math.h>

// ---------------------------------------------------------------------------
// Spherical CNN regression forward (MAXL=3, 2 layers, TAU_IN=16, TAU_H=32).
// 5-launch pipeline with SYMMETRY-REDUCED A: duplicate CG pairs (l2,l1) are
// never materialized; their weights are folded into the source pair's WT
// (W'_src = W_src + s*W_dup, s = (-1)^(l1+l2-L)) at WT-build time.
//   k_in_cg0:  [0..B/8)  front: parts->LDS, thread=(elem,c) full chain -> A
//              [B/8..+736) WT merge+realification (tiled + col-permuted)
//   k_gemm_all (layer0) -> HB   (verified structure, reduced K')
//   k_cg_all<true> (layer1 norm+CG, unique pairs) -> A
//   k_gemm_all (layer1) -> HA
//   k_final: norms + MLP -> out (verified)
// Unique K': L0=256, L1=384, L2=448, L3=384 (KT = 8,12,14,12). A = 51.9 MB.
// A layout: [mt][kt][lane=(kb*16+ar)][8 halves]; WT tiled [nt][kt][lane][8].
// ws layout: [WT 376832 B][HA B*2048 B][HB B*2048 B][A0|A1|A2|A3]
// Verified best: 94.6 us, absmax 1.95e-3 (rounds 16 and 19).
// ---------------------------------------------------------------------------

typedef _Float16 f16x8 __attribute__((ext_vector_type(8)));
typedef float f32x4 __attribute__((ext_vector_type(4)));

constexpr int kPS[5] = {0, 4, 13, 24, 34};
constexpr unsigned char kP1[34] = {
    0, 1, 2, 3,
    0, 1, 1, 1, 2, 2, 2, 3, 3,
    0, 1, 1, 1, 2, 2, 2, 2, 3, 3, 3,
    0, 1, 1, 2, 2, 2, 3, 3, 3, 3};
constexpr unsigned char kP2[34] = {
    0, 1, 2, 3,
    1, 0, 1, 2, 1, 2, 3, 2, 3,
    2, 1, 2, 3, 0, 1, 2, 3, 1, 2, 3,
    3, 2, 3, 1, 2, 3, 0, 1, 2, 3};
constexpr int kCGCoff[5] = {0, 28, 217, 602, 1092};
#define CGC_TOTAL 1092

// Unique-pair tables (first-occurrence order; dup = later (l2,l1) twin).
constexpr int kU_PS[5] = {0, 4, 10, 17, 23};
constexpr int kUsrc[23] = {0, 1, 2, 3,
                           0, 2, 3, 5, 6, 8,
                           0, 1, 2, 3, 6, 7, 10,
                           0, 1, 2, 4, 5, 9};
constexpr int kUdup[23] = {-1, -1, -1, -1,
                           1, -1, 4, -1, 7, -1,
                           4, -1, 5, 8, -1, 9, -1,
                           6, 3, 7, -1, 8, -1};
constexpr int kUsgn[23] = {1, 1, 1, 1,
                           1, 1, 1, 1, 1, 1,
                           1, 1, -1, 1, 1, -1, 1,
                           1, 1, -1, 1, 1, 1};
constexpr int kKpU[4] = {256, 384, 448, 384};        // unique K' per L
constexpr int kWToffU[4] = {0, 16384, 40960, 69632}; // half offsets within layer
#define WT_LAYER_U 94208                              // halves per layer

// ---------------- compile-time compact CG table ----------------------------
constexpr double cfact(int n) {
    double r = 1.0;
    for (int i = 2; i <= n; ++i) r *= (double)i;
    return r;
}
constexpr double csqrt(double x) {
    double g = (x > 1.0) ? x : 1.0;
    for (int it = 0; it < 64; ++it) g = 0.5 * (g + x / g);
    return g;
}
constexpr double cg_coef(int l1, int l2, int L, int m1, int m2) {
    int M = m1 + m2;
    double pre = csqrt((2.0 * L + 1.0) * cfact(l1 + l2 - L) * cfact(l1 - l2 + L) *
                       cfact(-l1 + l2 + L) / cfact(l1 + l2 + L + 1));
    pre *= csqrt(cfact(L + M) * cfact(L - M) * cfact(l1 - m1) * cfact(l1 + m1) *
                 cfact(l2 - m2) * cfact(l2 + m2));
    double s = 0.0;
    for (int k = 0; k <= l1 + l2 - L; ++k) {
        int u2 = l1 - m1 - k, u3 = l2 + m2 - k;
        int u4 = L - l2 + m1 + k, u5 = L - l1 - m2 + k;
        if (u2 < 0 || u3 < 0 || u4 < 0 || u5 < 0) continue;
        double d = cfact(k) * cfact(l1 + l2 - L - k) * cfact(u2) * cfact(u3) *
                   cfact(u4) * cfact(u5);
        s += ((k & 1) ? -1.0 : 1.0) / d;
    }
    return pre * s;
}
struct CGCTable {
    float v[CGC_TOTAL];
};
constexpr CGCTable makeCGC() {
    CGCTable T{};
    for (int t = 0; t < CGC_TOTAL; ++t) {
        int L = 0;
        while (t >= kCGCoff[L + 1]) ++L;
        int rloc = t - kCGCoff[L];
        int r = rloc / 7, i = rloc % 7;
        int nM = 2 * L + 1;
        int pl = r / nM, M = r % nM;
        int l1 = kP1[kPS[L] + pl], l2 = kP2[kPS[L] + pl];
        float val = 0.0f;
        int j = (M - L) - (i - l1) + l2;
        if (i <= 2 * l1 && j >= 0 && j <= 2 * l2)
            val = (float)cg_coef(l1, l2, L, i - l1, j - l2);
        T.v[t] = val;
    }
    return T;
}
constexpr CGCTable kCGC_CE = makeCGC();

// ---------------- compile-time CG product emission -------------------------
template <int LL>
__device__ __forceinline__ void norm_l(float2 (&hv)[16]) {
    float s = 0.f;
#pragma unroll
    for (int m = 0; m < 2 * LL + 1; ++m) {
        float2 v = hv[LL * LL + m];
        s += v.x * v.x + v.y * v.y;
    }
    float inv = 1.0f / sqrtf(s);
#pragma unroll
    for (int m = 0; m < 2 * LL + 1; ++m) {
        hv[LL * LL + m].x *= inv;
        hv[LL * LL + m].y *= inv;
    }
}

template <int L, int PS, int R, int I>
__device__ __forceinline__ void cg_term(const float2 (&hv)[16], float2& acc) {
    if constexpr (I < 7) {
        constexpr int nM = 2 * L + 1;
        constexpr int pl = R / nM, M = R % nM;
        constexpr int l1 = kP1[PS + pl], l2 = kP2[PS + pl];
        constexpr float coef = kCGC_CE.v[kCGCoff[L] + R * 7 + I];
        if constexpr (coef != 0.0f) {
            constexpr int jj = (M - L) - (I - l1) + l2;
            constexpr int s1 = l1 * l1 + I, s2 = l2 * l2 + jj;
            float2 a = hv[s1], b = hv[s2];
            acc.x += coef * (a.x * b.x - a.y * b.y);
            acc.y += coef * (a.x * b.y + a.y * b.x);
        }
        cg_term<L, PS, R, I + 1>(hv, acc);
    }
}

// Rows of unique pair U (source pair kUsrc): fragment-tiled store with new KT.
template <int L, int PS, int NU, int U, int M>
__device__ __forceinline__ void uRows(const float2 (&hv)[16], __half2* __restrict__ A2,
                                      int elemBase, int coff) {
    if constexpr (M < 2 * L + 1) {
        constexpr int PLo = kUsrc[kU_PS[L] + U];
        constexpr int KT = kKpU[L] / 32;
        float2 acc = make_float2(0.f, 0.f);
        cg_term<L, PS, PLo*(2 * L + 1) + M, 0>(hv, acc);
        int row = elemBase + M;
        A2[((row >> 4) * KT + 2 * U) * 256 + coff + ((row & 15) << 2)] =
            __float22half2_rn(acc);
        uRows<L, PS, NU, U, M + 1>(hv, A2, elemBase, coff);
    }
}

template <int L, int PS, int NU, int U>
__device__ __forceinline__ void pairEmitU(const float2 (&hv)[16],
                                          __half2* __restrict__ A2, int elemBase,
                                          int coff) {
    if constexpr (U < NU) {
        uRows<L, PS, NU, U, 0>(hv, A2, elemBase, coff);
        pairEmitU<L, PS, NU, U + 1>(hv, A2, elemBase, coff);
    }
}

template <int L, int PS, int NU, bool NORM>
__device__ __forceinline__ void cg_body(const __half2* __restrict__ Hin,
                                        __half2* __restrict__ A2, int elem, int c) {
    float2 hv[16];
#pragma unroll
    for (int s = 0; s < 16; ++s) hv[s] = __half22float2(Hin[elem * 512 + s * 32 + c]);
    if constexpr (NORM) {
        norm_l<0>(hv);
        norm_l<1>(hv);
        norm_l<2>(hv);
        norm_l<3>(hv);
    }
    const int coff = ((c >> 4) << 8) + (((c >> 2) & 3) << 6) + (c & 3);
    pairEmitU<L, PS, NU, 0>(hv, A2, elem * (2 * L + 1), coff);
}

// ---------------- per-thread input matmul (W cached in regs) ---------------
template <int LSET>
__device__ __forceinline__ void in_mm(const float2* __restrict__ stgE,
                                      const float* __restrict__ Wi, int c,
                                      float2 (&hv)[16]) {
    constexpr int s0 = LSET * LSET, ns = 2 * LSET + 1;
    float2 w[16];
#pragma unroll
    for (int k = 0; k < 16; ++k) w[k] = *(const float2*)(Wi + (k * 32 + c) * 2);
#pragma unroll
    for (int s = 0; s < ns; ++s) {
        float2 acc = make_float2(0.f, 0.f);
#pragma unroll
        for (int k = 0; k < 16; ++k) {
            float2 a = stgE[(s0 + s) * 16 + k];
            acc.x += a.x * w[k].x - a.y * w[k].y;
            acc.y += a.x * w[k].y + a.y * w[k].x;
        }
        hv[s0 + s] = acc;
    }
}

// ---------------- merged front kernel: input+norm+cg0  ||  WT --------------
__global__ void __launch_bounds__(256) k_in_cg0(
    const float* __restrict__ p0, const float* __restrict__ p1,
    const float* __restrict__ p2, const float* __restrict__ p3,
    const float* __restrict__ Wi0, const float* __restrict__ Wi1,
    const float* __restrict__ Wi2, const float* __restrict__ Wi3,
    const float* __restrict__ h00, const float* __restrict__ h01,
    const float* __restrict__ h02, const float* __restrict__ h03,
    const float* __restrict__ h10, const float* __restrict__ h11,
    const float* __restrict__ h12, const float* __restrict__ h13,
    __half* __restrict__ WT, __half2* __restrict__ A0, __half2* __restrict__ A1,
    __half2* __restrict__ A2_, __half2* __restrict__ A3, int nin) {
    const int tid = threadIdx.x;
    const int bid = blockIdx.x;

    if (bid >= nin) {
        // ---- WT merge + realification (unique pairs, tiled) ----
        int t = (bid - nin) * 256 + tid;  // [0, 2*WT_LAYER_U)
        int layer = t / WT_LAYER_U, rem = t % WT_LAYER_U;
        int L;
        if (rem < 16384) L = 0;
        else if (rem < 40960) L = 1;
        else if (rem < 69632) L = 2;
        else L = 3;
        int rem2 = rem - kWToffU[L];
        int KT = kKpU[L] / 32;
        int tile = rem2 >> 9, within = rem2 & 511;
        int lane = within >> 3, e8 = within & 7;
        int nt = tile / KT, kt = tile - nt * KT;
        int nr = lane & 15, kb = lane >> 4;
        int np = 2 * nr + (nt & 1) + 32 * (nt >> 1);  // col-perm
        int kp = kt * 32 + kb * 8 + e8;
        int q = kp >> 1, s = kp & 1, cW = np >> 1, tt = np & 1;
        int u = q >> 5, qloc = q & 31;
        int ub = kU_PS[L] + u;
        int PLo = kUsrc[ub], PDo = kUdup[ub];
        float sg = (float)kUsgn[ub];
        const float* W = (layer == 0) ? (L == 0 ? h00 : L == 1 ? h01 : L == 2 ? h02 : h03)
                                      : (L == 0 ? h10 : L == 1 ? h11 : L == 2 ? h12 : h13);
        float wr = W[((PLo * 32 + qloc) * 32 + cW) * 2];
        float wi = W[((PLo * 32 + qloc) * 32 + cW) * 2 + 1];
        if (PDo >= 0) {
            wr += sg * W[((PDo * 32 + qloc) * 32 + cW) * 2];
            wi += sg * W[((PDo * 32 + qloc) * 32 + cW) * 2 + 1];
        }
        float v = (tt == 0) ? (s == 0 ? wr : -wi) : (s == 0 ? wi : wr);
        WT[t] = __float2half(v);
        return;
    }

    // ---- stage parts for 8 elements ----
    __shared__ float2 stg[8][256];
    for (int idx = tid; idx < 2048; idx += 256) {
        int e = idx >> 8, r = idx & 255;
        int slot = r >> 4, k = r & 15;
        int l = (slot >= 9) + (slot >= 4) + (slot >= 1);
        int m = slot - l * l;
        const float* src = (l == 0) ? p0 : (l == 1) ? p1 : (l == 2) ? p2 : p3;
        src += ((size_t)((bid * 8 + e) * (2 * l + 1) + m) * 16 + k) * 2;
        stg[e][r] = make_float2(src[0], src[1]);
    }
    __syncthreads();

    // ---- thread (elem, c): matmul -> norm -> CG (unique pairs) ----
    const int e = tid >> 5, c = tid & 31;
    const int elem = bid * 8 + e;
    const float2* stgE = &stg[e][0];
    float2 hv[16];
    in_mm<0>(stgE, Wi0, c, hv);
    in_mm<1>(stgE, Wi1, c, hv);
    in_mm<2>(stgE, Wi2, c, hv);
    in_mm<3>(stgE, Wi3, c, hv);
    norm_l<0>(hv);
    norm_l<1>(hv);
    norm_l<2>(hv);
    norm_l<3>(hv);

    const int coff = ((c >> 4) << 8) + (((c >> 2) & 3) << 6) + (c & 3);
    pairEmitU<0, 0, 4, 0>(hv, A0, elem * 1, coff);
    pairEmitU<1, 4, 6, 0>(hv, A1, elem * 3, coff);
    pairEmitU<2, 13, 7, 0>(hv, A2_, elem * 5, coff);
    pairEmitU<3, 24, 6, 0>(hv, A3, elem * 7, coff);
}

// ---------------- CG layer-1 kernel (unique pairs) -------------------------
template <bool NORM>
__global__ void __launch_bounds__(256) k_cg_all(const __half2* __restrict__ Hin,
                                                __half2* __restrict__ A0,
                                                __half2* __restrict__ A1,
                                                __half2* __restrict__ A2_,
                                                __half2* __restrict__ A3, int nbseg) {
    const int tid = threadIdx.x;
    const int wave = tid >> 6, lane = tid & 63;
    const int c = lane & 31, h = lane >> 5;
    int bid = blockIdx.x;
    if (bid < nbseg) {
        int elem = (bid * 4 + wave) * 2 + h;
        cg_body<0, 0, 4, NORM>(Hin, A0, elem, c);
    } else if (bid < 2 * nbseg) {
        int elem = ((bid - nbseg) * 4 + wave) * 2 + h;
        cg_body<1, 4, 6, NORM>(Hin, A1, elem, c);
    } else if (bid < 3 * nbseg) {
        int elem = ((bid - 2 * nbseg) * 4 + wave) * 2 + h;
        cg_body<2, 13, 7, NORM>(Hin, A2_, elem, c);
    } else {
        int elem = ((bid - 3 * nbseg) * 4 + wave) * 2 + h;
        cg_body<3, 24, 6, NORM>(Hin, A3, elem, c);
    }
}

// ---------------- GEMM (verified structure, reduced K') --------------------
template <int L>
__device__ __forceinline__ void gemm_body(const _Float16* __restrict__ A,
                                          const _Float16* __restrict__ WT,
                                          __half2* __restrict__ Hout, int blk, int tid) {
    constexpr int nM = 2 * L + 1, KT = kKpU[L] / 32;
    const int wave = tid >> 6, lane = tid & 63;
    const int mt0 = blk * 8 + wave * 2, mt1 = mt0 + 1;
    const int ar = lane & 15, kb = lane >> 4;

    const _Float16* Ap0 = A + (size_t)(mt0 * KT) * 512 + lane * 8;
    const _Float16* Ap1 = A + (size_t)(mt1 * KT) * 512 + lane * 8;
    const _Float16* Wp = WT + lane * 8;

    f32x4 d00 = {0.f, 0.f, 0.f, 0.f}, d01 = d00, d02 = d00, d03 = d00;
    f32x4 d10 = d00, d11 = d00, d12 = d00, d13 = d00;
#pragma unroll 2
    for (int kt = 0; kt < KT; ++kt) {
        f16x8 a0 = *(const f16x8*)(Ap0 + kt * 512);
        f16x8 a1 = *(const f16x8*)(Ap1 + kt * 512);
        f16x8 w0 = *(const f16x8*)(Wp + (0 * KT + kt) * 512);
        f16x8 w1 = *(const f16x8*)(Wp + (1 * KT + kt) * 512);
        f16x8 w2 = *(const f16x8*)(Wp + (2 * KT + kt) * 512);
        f16x8 w3 = *(const f16x8*)(Wp + (3 * KT + kt) * 512);
        d00 = __builtin_amdgcn_mfma_f32_16x16x32_f16(a0, w0, d00, 0, 0, 0);
        d01 = __builtin_amdgcn_mfma_f32_16x16x32_f16(a0, w1, d01, 0, 0, 0);
        d02 = __builtin_amdgcn_mfma_f32_16x16x32_f16(a0, w2, d02, 0, 0, 0);
        d03 = __builtin_amdgcn_mfma_f32_16x16x32_f16(a0, w3, d03, 0, 0, 0);
        d10 = __builtin_amdgcn_mfma_f32_16x16x32_f16(a1, w0, d10, 0, 0, 0);
        d11 = __builtin_amdgcn_mfma_f32_16x16x32_f16(a1, w1, d11, 0, 0, 0);
        d12 = __builtin_amdgcn_mfma_f32_16x16x32_f16(a1, w2, d12, 0, 0, 0);
        d13 = __builtin_amdgcn_mfma_f32_16x16x32_f16(a1, w3, d13, 0, 0, 0);
    }

    const int rowb0 = mt0 * 16 + kb * 4, rowb1 = mt1 * 16 + kb * 4;
#pragma unroll
    for (int r = 0; r < 4; ++r) {
        int row = rowb0 + r;
        int e = row / nM, M = row - e * nM;
        int base = e * 512 + (L * L + M) * 32;
        Hout[base + ar] = __floats2half2_rn(d00[r], d01[r]);
        Hout[base + 16 + ar] = __floats2half2_rn(d02[r], d03[r]);
    }
#pragma unroll
    for (int r = 0; r < 4; ++r) {
        int row = rowb1 + r;
        int e = row / nM, M = row - e * nM;
        int base = e * 512 + (L * L + M) * 32;
        Hout[base + ar] = __floats2half2_rn(d10[r], d11[r]);
        Hout[base + 16 + ar] = __floats2half2_rn(d12[r], d13[r]);
    }
}

__global__ void __launch_bounds__(256) k_gemm_all(
    const _Float16* __restrict__ A0, const _Float16* __restrict__ A1,
    const _Float16* __restrict__ A2_, const _Float16* __restrict__ A3,
    const _Float16* __restrict__ WT, __half2* __restrict__ Hout, int nb) {
    const int tid = threadIdx.x;
    int bid = blockIdx.x;
    if (bid < nb) {
        gemm_body<0>(A0, WT + kWToffU[0], Hout, bid, tid);
    } else if (bid < 4 * nb) {
        gemm_body<1>(A1, WT + kWToffU[1], Hout, bid - nb, tid);
    } else if (bid < 9 * nb) {
        gemm_body<2>(A2_, WT + kWToffU[2], Hout, bid - 4 * nb, tid);
    } else {
        gemm_body<3>(A3, WT + kWToffU[3], Hout, bid - 9 * nb, tid);
    }
}

// ---------------- final norms + MLP (verified) -----------------------------
__global__ void __launch_bounds__(128) k_final(const __half2* __restrict__ H,
                                               const float* __restrict__ W1,
                                               const float* __restrict__ b1,
                                               const float* __restrict__ W2,
                                               const float* __restrict__ b2,
                                               float* __restrict__ out) {
    __shared__ float shv[392];
    const int tid = threadIdx.x, b = blockIdx.x;
    {
        int l = tid >> 5, c = tid & 31, off = l * l, n = 2 * l + 1;
        float s = 0.f;
        for (int m = 0; m < n; ++m) {
            float2 v = __half22float2(H[b * 512 + (off + m) * 32 + c]);
            s += v.x * v.x + v.y * v.y;
        }
        shv[tid] = sqrtf(s);
    }
    __syncthreads();
#pragma unroll
    for (int rr = 0; rr < 2; ++rr) {
        int j = tid + rr * 128;
        float acc = b1[j];
        for (int i = 0; i < 128; ++i) acc += shv[i] * W1[i * 256 + j];
        shv[128 + j] = tanhf(acc);
    }
    __syncthreads();
    float partial = shv[128 + tid] * W2[tid] + shv[256 + tid] * W2[tid + 128];
#pragma unroll
    for (int off = 32; off > 0; off >>= 1) partial += __shfl_down(partial, off);
    if ((tid & 63) == 0) shv[384 + (tid >> 6)] = partial;
    __syncthreads();
    if (tid == 0) out[b] = shv[384] + shv[385] + b2[0];
}

extern "C" void kernel_launch(void* const* d_in, const int* in_sizes, int n_in,
                              void* d_out, int out_size, void* d_ws, size_t ws_size,
                              hipStream_t stream) {
    (void)n_in;
    (void)ws_size;
    (void)out_size;
    const int B = in_sizes[0] / 32;  // part_0 is [B,1,16,2]

    char* ws = (char*)d_ws;
    // ws layout (bytes): WT | HA | HB | A0 | A1 | A2 | A3
    __half* WTh = (__half*)ws;
    _Float16* WTf = (_Float16*)ws;
    size_t off = 376832;  // 2*WT_LAYER_U*2 bytes
    __half2* HA = (__half2*)(ws + off);
    off += (size_t)B * 2048;
    __half2* HB = (__half2*)(ws + off);
    off += (size_t)B * 2048;
    __half* Ab = (__half*)(ws + off);
    // per-L A offsets in halves: sizes B*nM*KpU
    size_t a0 = 0;
    size_t a1 = a0 + (size_t)B * 1 * 256;
    size_t a2 = a1 + (size_t)B * 3 * 384;
    size_t a3 = a2 + (size_t)B * 5 * 448;

    __half2* A0h = (__half2*)(Ab + a0);
    __half2* A1h = (__half2*)(Ab + a1);
    __half2* A2h = (__half2*)(Ab + a2);
    __half2* A3h = (__half2*)(Ab + a3);
    _Float16* A0f = (_Float16*)(Ab + a0);
    _Float16* A1f = (_Float16*)(Ab + a1);
    _Float16* A2f = (_Float16*)(Ab + a2);
    _Float16* A3f = (_Float16*)(Ab + a3);

    const int nin = B / 8;
    const int nwt = 2 * WT_LAYER_U / 256;  // 736
    const int nbseg = B / 8, nb = B / 128;

    // ---- front: input+norm+cg0 || WT ----
    hipLaunchKernelGGL(k_in_cg0, dim3(nin + nwt), dim3(256), 0, stream,
                       (const float*)d_in[0], (const float*)d_in[1],
                       (const float*)d_in[2], (const float*)d_in[3],
                       (const float*)d_in[4], (const float*)d_in[5],
                       (const float*)d_in[6], (const float*)d_in[7],
                       (const float*)d_in[8], (const float*)d_in[9],
                       (const float*)d_in[10], (const float*)d_in[11],
                       (const float*)d_in[12], (const float*)d_in[13],
                       (const float*)d_in[14], (const float*)d_in[15], WTh, A0h, A1h,
                       A2h, A3h, nin);

    // ---- layer 0 GEMM -> HB ----
    hipLaunchKernelGGL(k_gemm_all, dim3(16 * nb), dim3(256), 0, stream,
                       A0f, A1f, A2f, A3f, WTf + 0 * WT_LAYER_U, HB, nb);

    // ---- layer 1: CG (normalize) -> A ----
    hipLaunchKernelGGL((k_cg_all<true>), dim3(4 * nbseg), dim3(256), 0, stream, HB,
                       A0h, A1h, A2h, A3h, nbseg);

    // ---- layer 1 GEMM -> HA ----
    hipLaunchKernelGGL(k_gemm_all, dim3(16 * nb), dim3(256), 0, stream,
                       A0f, A1f, A2f, A3f, WTf + 1 * WT_LAYER_U, HA, nb);

    // ---- final ----
    hipLaunchKernelGGL(k_final, dim3(B), dim3(128), 0, stream, HA,
                       (const float*)d_in[16], (const float*)d_in[17],
                       (const float*)d_in[18], (const float*)d_in[19], (float*)d_out);
}